// Round 8
// baseline (399.377 us; speedup 1.0000x reference)
//
#include <hip/hip_runtime.h>

#define NPOS 288
#define NCH 6
#define CHUNK 48
#define CSTRIDE 36               // floats per c-row in partials (144 B, 16B-aligned)
#define PSTRIDE (32 * CSTRIDE)   // floats per (pos,chunk) record = 1152

// ---- DPP 32-lane reductions (VALU pipe; groups = lanes [0,32),[32,64)) ----
template<int CTRL>
__device__ __forceinline__ float dpp_mov(float x) {
    return __int_as_float(__builtin_amdgcn_update_dpp(
        0, __float_as_int(x), CTRL, 0xF, 0xF, true));
}
__device__ __forceinline__ float red32_max(float x) {
    x = fmaxf(x, dpp_mov<0x121>(x));
    x = fmaxf(x, dpp_mov<0x122>(x));
    x = fmaxf(x, dpp_mov<0x124>(x));
    x = fmaxf(x, dpp_mov<0x128>(x));
    return fmaxf(x, __shfl_xor(x, 16));
}
__device__ __forceinline__ float red32_sum(float x) {
    x += dpp_mov<0x121>(x);
    x += dpp_mov<0x122>(x);
    x += dpp_mov<0x124>(x);
    x += dpp_mov<0x128>(x);
    return x + __shfl_xor(x, 16);
}

#define DOT4(pa, c0, c1, c2, c3) fmaf(pa.x, c0, fmaf(pa.y, c1, fmaf(pa.z, c2, pa.w * c3)))
#define VROWS() \
    v0.x = DOT4(pa0, wa0.x, wa1.x, wa2.x, wa3.x); \
    v0.y = DOT4(pa0, wa0.y, wa1.y, wa2.y, wa3.y); \
    v0.z = DOT4(pa0, wa0.z, wa1.z, wa2.z, wa3.z); \
    v0.w = DOT4(pa0, wa0.w, wa1.w, wa2.w, wa3.w); \
    v1.x = DOT4(pa1, wa0.x, wa1.x, wa2.x, wa3.x); \
    v1.y = DOT4(pa1, wa0.y, wa1.y, wa2.y, wa3.y); \
    v1.z = DOT4(pa1, wa0.z, wa1.z, wa2.z, wa3.z); \
    v1.w = DOT4(pa1, wa0.w, wa1.w, wa2.w, wa3.w); \
    v2.x = DOT4(pa2, wa0.x, wa1.x, wa2.x, wa3.x); \
    v2.y = DOT4(pa2, wa0.y, wa1.y, wa2.y, wa3.y); \
    v2.z = DOT4(pa2, wa0.z, wa1.z, wa2.z, wa3.z); \
    v2.w = DOT4(pa2, wa0.w, wa1.w, wa2.w, wa3.w); \
    v3.x = DOT4(pa3, wa0.x, wa1.x, wa2.x, wa3.x); \
    v3.y = DOT4(pa3, wa0.y, wa1.y, wa2.y, wa3.y); \
    v3.z = DOT4(pa3, wa0.z, wa1.z, wa2.z, wa3.z); \
    v3.w = DOT4(pa3, wa0.w, wa1.w, wa2.w, wa3.w);
#define SQ4(d, v) d.x = v.x*v.x; d.y = v.y*v.y; d.z = v.z*v.z; d.w = v.w*v.w;
#define TU4(t, u, v, q, A, B) \
    t = fmaf(q.x, A.x, t); u = fmaf(v.x, B.x, u); \
    t = fmaf(q.y, A.y, t); u = fmaf(v.y, B.y, u); \
    t = fmaf(q.z, A.z, t); u = fmaf(v.z, B.z, u); \
    t = fmaf(q.w, A.w, t); u = fmaf(v.w, B.w, u);
#define RACC(mai, vai, vi, qi) \
    mai.x = fmaf(r, vi.x, mai.x); vai.x = fmaf(r, qi.x, vai.x); \
    mai.y = fmaf(r, vi.y, mai.y); vai.y = fmaf(r, qi.y, vai.y); \
    mai.z = fmaf(r, vi.z, mai.z); vai.z = fmaf(r, qi.z, vai.z); \
    mai.w = fmaf(r, vi.w, mai.w); vai.w = fmaf(r, qi.w, vai.w);
#define XRED(vi) \
    vi.x += __shfl_xor(vi.x, 32); vi.y += __shfl_xor(vi.y, 32); \
    vi.z += __shfl_xor(vi.z, 32); vi.w += __shfl_xor(vi.w, 32);

// ---------------------------------------------------------------------------
// Pipeline: 3 accumulate kernels (one per EM iteration); finalize fused into
// acc<2> via last-block-per-pos atomic. Grid 1728 = 288 pos x 6 chunks of 48 n.
// E-step uses expanded quadratic: lnap = 2*sum(v*B) - sum(v^2*A) - C with
// A=i2s, B=mu*i2s, C=sum(mu^2*i2s)+Kc; v^2 shared with M-step (5 ops/p vs 6).
// PLAIN __launch_bounds__ only (R1/R4: min-waves arg => spill catastrophe).
// ---------------------------------------------------------------------------
template<int IT>
__global__ __launch_bounds__(256) void caps_acc(
    const float* __restrict__ xg,
    const float* __restrict__ ag,
    const float* __restrict__ wg,
    const float* __restrict__ bu,
    const float* __restrict__ ba,
    const float* __restrict__ pin,   // previous-iteration partials (IT>0)
    float* __restrict__ pout,        // this-iteration partials
    float* __restrict__ outg,        // final outputs (IT==2)
    unsigned* __restrict__ cnt)      // per-pos arrival counters (IT==0 zeroes, IT==2 uses)
{
    __shared__ __align__(16) float pose_s[CHUNK * 16];   // 48 n x 16 p = 3KB
    __shared__ float a_s[CHUNK];
    __shared__ __align__(16) float scratch[4 * 32 * 33]; // 4 waves x 32 c x 33
    __shared__ float rsum_part[4 * 32];
    __shared__ float i2s_tab[512];                       // A
    __shared__ float b_tab[512];                         // B = mu*i2s
    __shared__ float c_tab[32];                          // C = M2 + Kc
    __shared__ int   last_s;

    const int tid = threadIdx.x;
    const int blk = blockIdx.x;
    const int pos = blk / NCH;
    const int ch  = blk - pos * NCH;
    const int bb  = pos / 36;
    const int rem = pos % 36;
    const int yy  = rem / 6;
    const int xx  = rem % 6;

    // ---- stage pose slice (48x16); 256-wide loads never cross a cell ----
    #pragma unroll
    for (int j = 0; j < 3; ++j) {
        const int e    = ch * 768 + j * 256 + tid;
        const int cell = e >> 9;
        const int off  = e & 511;
        const int kh = cell / 3, kw = cell % 3;
        pose_s[j * 256 + tid] =
            xg[(size_t)((((bb * 14) + (2 * yy + kh)) * 14 + (2 * xx + kw)) * 32) * 16 + off];
    }
    if (IT == 0) {
        if (tid < CHUNK) {
            const int e    = ch * CHUNK + tid;
            const int cell = e >> 5;
            const int bi   = e & 31;
            const int kh = cell / 3, kw = cell % 3;
            a_s[tid] = ag[(size_t)(((bb * 14) + (2 * yy + kh)) * 14 + (2 * xx + kw)) * 32 + bi];
        }
        if (ch == 0 && tid == 0) cnt[pos] = 0u;   // used by acc<2>, 2 dispatches later
    }

    const int fc2 = tid >> 3;   // 0..31
    const int fh  = tid & 7;    // 0..7
    if (IT > 0) {
        // ---- redundant finalize of previous iteration from global partials ----
        const float* q0 = pin + (size_t)pos * (NCH * PSTRIDE) + fc2 * CSTRIDE;
        float ms0 = 0.f, ms1 = 0.f, vs0 = 0.f, vs1 = 0.f, rsc = 0.f;
        #pragma unroll
        for (int cc = 0; cc < NCH; ++cc) {
            const float* q = q0 + cc * PSTRIDE;
            const float4 m4 = *(const float4*)&q[fh * 4];
            ms0 += m4.x; ms1 += m4.y; vs0 += m4.z; vs1 += m4.w;
            rsc += q[32];
        }
        const float inv  = 1.f / (rsc + 1e-6f);
        const float S    = rsc * inv;
        const float mmu0 = ms0 * inv;
        const float mmu1 = ms1 * inv;
        const float sg0  = vs0 * inv - mmu0 * mmu0 * (2.f - S) + 1e-6f;
        const float sg1  = vs1 * inv - mmu1 * mmu1 * (2.f - S) + 1e-6f;
        const float i0   = 0.5f / sg0;
        const float i1   = 0.5f / sg1;
        float lgs = __logf(sg0) + __logf(sg1);
        float m2  = fmaf(mmu0 * mmu0, i0, mmu1 * mmu1 * i1);
        #pragma unroll
        for (int msk = 4; msk >= 1; msk >>= 1) {
            lgs += __shfl_xor(lgs, msk);
            m2  += __shfl_xor(m2, msk);
        }
        const float cost = rsc * (16.f * bu[fc2] + 0.5f * lgs);
        const float ao   = 1.f / (1.f + __expf(-0.001f * (ba[fc2] - cost)));
        i2s_tab[fc2 * 16 + fh]     = i0;
        i2s_tab[fc2 * 16 + fh + 8] = i1;
        b_tab[fc2 * 16 + fh]       = mmu0 * i0;
        b_tab[fc2 * 16 + fh + 8]   = mmu1 * i1;
        if (fh == 0) c_tab[fc2] = m2 + 0.5f * lgs - __logf(ao);
    }
    __syncthreads();

    const int c    = tid & 31;
    const int s    = tid >> 5;
    const int lane = tid & 63;
    const int wv   = tid >> 6;
    const float4* wp = (const float4*)wg;

    float4 A0, A1, A2, A3, B0, B1, B2, B3;
    float C = 0.f;
    if (IT > 0) {
        A0 = *(const float4*)&i2s_tab[c * 16 + 0];
        A1 = *(const float4*)&i2s_tab[c * 16 + 4];
        A2 = *(const float4*)&i2s_tab[c * 16 + 8];
        A3 = *(const float4*)&i2s_tab[c * 16 + 12];
        B0 = *(const float4*)&b_tab[c * 16 + 0];
        B1 = *(const float4*)&b_tab[c * 16 + 4];
        B2 = *(const float4*)&b_tab[c * 16 + 8];
        B3 = *(const float4*)&b_tab[c * 16 + 12];
        C  = c_tab[c];
    }

    float4 ma0, ma1, ma2, ma3, va0, va1, va2, va3;
    ma0 = ma1 = ma2 = ma3 = make_float4(0.f, 0.f, 0.f, 0.f);
    va0 = va1 = va2 = va3 = make_float4(0.f, 0.f, 0.f, 0.f);
    float rs = 0.f;

    const int n0 = ch * CHUNK + s * 6;
    const float4* wptr = wp + (size_t)(n0 * 32 + c) * 4;
    float4 wa0 = wptr[0], wa1 = wptr[1], wa2 = wptr[2], wa3 = wptr[3];

    #define EM_STEP_ACC(NL)                                                \
    {                                                                      \
        const float4* pp = (const float4*)&pose_s[(NL) << 4];              \
        float4 pa0 = pp[0], pa1 = pp[1], pa2 = pp[2], pa3 = pp[3];         \
        float4 v0, v1, v2, v3;                                             \
        VROWS()                                                            \
        float4 q0_, q1_, q2_, q3_;                                         \
        SQ4(q0_, v0) SQ4(q1_, v1) SQ4(q2_, v2) SQ4(q3_, v3)                \
        float r;                                                           \
        if (IT == 0) {                                                     \
            r = a_s[NL] * 0.03125f;                                        \
        } else {                                                           \
            float t01 = 0.f, u01 = 0.f, t23 = 0.f, u23 = 0.f;              \
            TU4(t01, u01, v0, q0_, A0, B0)                                 \
            TU4(t01, u01, v1, q1_, A1, B1)                                 \
            TU4(t23, u23, v2, q2_, A2, B2)                                 \
            TU4(t23, u23, v3, q3_, A3, B3)                                 \
            const float lnap = fmaf(2.f, u01 + u23, -(t01 + t23)) - C;     \
            const float m    = red32_max(lnap);                            \
            const float e    = __expf(lnap - m);                           \
            const float sum  = red32_sum(e);                               \
            r = __fdividef(e, sum);                                        \
        }                                                                  \
        rs += r;                                                           \
        RACC(ma0, va0, v0, q0_)                                            \
        RACC(ma1, va1, v1, q1_)                                            \
        RACC(ma2, va2, v2, q2_)                                            \
        RACC(ma3, va3, v3, q3_)                                            \
    }

    for (int k = 0; k < 5; ++k) {
        const float4* wnext = wptr + 128;
        float4 wn0 = wnext[0], wn1 = wnext[1], wn2 = wnext[2], wn3 = wnext[3];
        EM_STEP_ACC(s * 6 + k)
        wa0 = wn0; wa1 = wn1; wa2 = wn2; wa3 = wn3; wptr = wnext;
    }
    EM_STEP_ACC(s * 6 + 5)
    #undef EM_STEP_ACC

    // ---- reduce 8 n-slices: shfl pair, then LDS across 4 waves ----
    XRED(ma0) XRED(ma1) XRED(ma2) XRED(ma3)
    XRED(va0) XRED(va1) XRED(va2) XRED(va3)
    rs += __shfl_xor(rs, 32);
    if (lane < 32) {  // c = lane
        const int base = (wv * 32 + lane) * 33;
        scratch[base+0]=ma0.x;  scratch[base+1]=ma0.y;  scratch[base+2]=ma0.z;  scratch[base+3]=ma0.w;
        scratch[base+4]=ma1.x;  scratch[base+5]=ma1.y;  scratch[base+6]=ma1.z;  scratch[base+7]=ma1.w;
        scratch[base+8]=ma2.x;  scratch[base+9]=ma2.y;  scratch[base+10]=ma2.z; scratch[base+11]=ma2.w;
        scratch[base+12]=ma3.x; scratch[base+13]=ma3.y; scratch[base+14]=ma3.z; scratch[base+15]=ma3.w;
        scratch[base+16]=va0.x; scratch[base+17]=va0.y; scratch[base+18]=va0.z; scratch[base+19]=va0.w;
        scratch[base+20]=va1.x; scratch[base+21]=va1.y; scratch[base+22]=va1.z; scratch[base+23]=va1.w;
        scratch[base+24]=va2.x; scratch[base+25]=va2.y; scratch[base+26]=va2.z; scratch[base+27]=va2.w;
        scratch[base+28]=va3.x; scratch[base+29]=va3.y; scratch[base+30]=va3.z; scratch[base+31]=va3.w;
        rsum_part[wv * 32 + lane] = rs;
    }
    __syncthreads();

    // ---- block-level sum -> write chunk partials ([fh][ms0,ms1,vs0,vs1] rows) ----
    float ms0 = 0.f, ms1 = 0.f, vs0 = 0.f, vs1 = 0.f, rsc = 0.f;
    #pragma unroll
    for (int w = 0; w < 4; ++w) {
        const int base = (w * 32 + fc2) * 33;
        ms0 += scratch[base + fh];
        ms1 += scratch[base + fh + 8];
        vs0 += scratch[base + 16 + fh];
        vs1 += scratch[base + 16 + fh + 8];
        rsc += rsum_part[w * 32 + fc2];
    }
    float* po = pout + (size_t)(pos * NCH + ch) * PSTRIDE + fc2 * CSTRIDE;
    *(float4*)&po[fh * 4] = make_float4(ms0, ms1, vs0, vs1);
    if (fh == 0) po[32] = rsc;

    if (IT == 2) {
        // ---- last chunk-block for this pos finalizes and writes outputs ----
        __threadfence();                       // release this block's partials (device scope)
        __syncthreads();
        if (tid == 0) last_s = (atomicAdd(&cnt[pos], 1u) == NCH - 1u);
        __syncthreads();
        if (last_s) {
            __threadfence();                   // acquire other blocks' partials
            const int fp = tid & 15;
            #pragma unroll
            for (int half = 0; half < 2; ++half) {
                const int fc = (tid >> 4) + half * 16;
                const float* qq = pout + (size_t)pos * (NCH * PSTRIDE) + fc * CSTRIDE;
                float ms = 0.f, vs = 0.f, rc = 0.f;
                #pragma unroll
                for (int cc = 0; cc < NCH; ++cc) {
                    const float* q = qq + cc * PSTRIDE;
                    ms += q[(fp & 7) * 4 + (fp >> 3)];
                    vs += q[(fp & 7) * 4 + 2 + (fp >> 3)];
                    rc += q[32];
                }
                const float inv = 1.f / (rc + 1e-6f);
                const float S   = rc * inv;
                const float mu  = ms * inv;
                const float sig = vs * inv - mu * mu * (2.f - S) + 1e-6f;
                float lgs = __logf(sig);
                #pragma unroll
                for (int msk = 8; msk >= 1; msk >>= 1) lgs += __shfl_xor(lgs, msk);
                const float cost = rc * (16.f * bu[fc] + 0.5f * lgs);
                const float ao   = 1.f / (1.f + __expf(-0.001f * (ba[fc] - cost)));
                outg[(size_t)pos * 512 + fc * 16 + fp] = mu;
                if (fp == 0) outg[147456 + (size_t)pos * 32 + fc] = ao;
            }
        }
    }
}

// ---------------------------------------------------------------------------
// Fallback: single fused kernel (used only if workspace too small).
// ---------------------------------------------------------------------------
__global__ __launch_bounds__(512) void convcaps_kernel(
    const float* __restrict__ xg,
    const float* __restrict__ ag,
    const float* __restrict__ wg,
    const float* __restrict__ bu,
    const float* __restrict__ ba,
    float* __restrict__ outp)
{
    __shared__ __align__(16) float pose_s[4608];
    __shared__ float a_s[288];
    __shared__ __align__(16) float scratch[8448];
    __shared__ float rsum_part[256];
    __shared__ float mu_tab[512];
    __shared__ float i2s_tab[512];
    __shared__ float Kc_tab[32];

    const int tid = threadIdx.x;
    const int pos = blockIdx.x;
    const int bb  = pos / 36;
    const int rem = pos % 36;
    const int yy  = rem / 6;
    const int xx  = rem % 6;

    #pragma unroll
    for (int wi = 0; wi < 9; ++wi) {
        const int kh = wi / 3, kw = wi % 3;
        const float* src =
            xg + (size_t)((((bb * 14) + (2 * yy + kh)) * 14 + (2 * xx + kw)) * 32) * 16;
        pose_s[wi * 512 + tid] = src[tid];
    }
    if (tid < 288) {
        const int wi = tid >> 5, bi = tid & 31;
        const int kh = wi / 3, kw = wi % 3;
        a_s[tid] = ag[(size_t)(((bb * 14) + (2 * yy + kh)) * 14 + (2 * xx + kw)) * 32 + bi];
    }
    __syncthreads();

    const int c    = tid & 31;
    const int s    = tid >> 5;
    const int lane = tid & 63;
    const int wv   = tid >> 6;
    const float4* wp = (const float4*)wg;

    for (int it = 0; it < 3; ++it) {
        float mu_c[16], i2s_c[16], Kc = 0.f;
        if (it > 0) {
            #pragma unroll
            for (int p = 0; p < 16; ++p) {
                mu_c[p]  = mu_tab[c * 16 + p];
                i2s_c[p] = i2s_tab[c * 16 + p];
            }
            Kc = Kc_tab[c];
        }
        float macc[16], vacc[16], rs = 0.f;
        #pragma unroll
        for (int p = 0; p < 16; ++p) { macc[p] = 0.f; vacc[p] = 0.f; }

        for (int k = 0; k < 18; ++k) {
            const int n = s * 18 + k;
            const float4* pp = (const float4*)&pose_s[n << 4];
            float pf[16];
            float4 q;
            q = pp[0]; pf[0]=q.x; pf[1]=q.y; pf[2]=q.z;  pf[3]=q.w;
            q = pp[1]; pf[4]=q.x; pf[5]=q.y; pf[6]=q.z;  pf[7]=q.w;
            q = pp[2]; pf[8]=q.x; pf[9]=q.y; pf[10]=q.z; pf[11]=q.w;
            q = pp[3]; pf[12]=q.x; pf[13]=q.y; pf[14]=q.z; pf[15]=q.w;
            const int wbase = (n * 32 + c) * 4;
            float v[16];
            #pragma unroll
            for (int p = 0; p < 16; ++p) v[p] = 0.f;
            #pragma unroll
            for (int j = 0; j < 4; ++j) {
                const float4 w = wp[wbase + j];
                #pragma unroll
                for (int i = 0; i < 4; ++i) {
                    const float pj = pf[i * 4 + j];
                    v[i*4+0] = fmaf(pj, w.x, v[i*4+0]);
                    v[i*4+1] = fmaf(pj, w.y, v[i*4+1]);
                    v[i*4+2] = fmaf(pj, w.z, v[i*4+2]);
                    v[i*4+3] = fmaf(pj, w.w, v[i*4+3]);
                }
            }
            float r;
            if (it == 0) {
                r = a_s[n] * 0.03125f;
            } else {
                float t = 0.f;
                #pragma unroll
                for (int p = 0; p < 16; ++p) {
                    float d = v[p] - mu_c[p];
                    t = fmaf(d * d, i2s_c[p], t);
                }
                float lnap = -t - Kc;
                float m = lnap;
                #pragma unroll
                for (int msk = 16; msk >= 1; msk >>= 1) m = fmaxf(m, __shfl_xor(m, msk));
                float e = __expf(lnap - m);
                float sum = e;
                #pragma unroll
                for (int msk = 16; msk >= 1; msk >>= 1) sum += __shfl_xor(sum, msk);
                r = e / sum;
            }
            rs += r;
            #pragma unroll
            for (int p = 0; p < 16; ++p) {
                float rv = r * v[p];
                macc[p] += rv;
                vacc[p] = fmaf(rv, v[p], vacc[p]);
            }
        }

        #pragma unroll
        for (int p = 0; p < 16; ++p) {
            macc[p] += __shfl_xor(macc[p], 32);
            vacc[p] += __shfl_xor(vacc[p], 32);
        }
        rs += __shfl_xor(rs, 32);
        if (lane < 32) {
            const int base = (wv * 32 + lane) * 33;
            #pragma unroll
            for (int p = 0; p < 16; ++p) {
                scratch[base + p]      = macc[p];
                scratch[base + 16 + p] = vacc[p];
            }
            rsum_part[wv * 32 + lane] = rs;
        }
        __syncthreads();

        const int fc = tid >> 4, fp = tid & 15;
        float ms = 0.f, vs = 0.f, rsc = 0.f;
        #pragma unroll
        for (int w = 0; w < 8; ++w) {
            ms  += scratch[(w * 32 + fc) * 33 + fp];
            vs  += scratch[(w * 32 + fc) * 33 + 16 + fp];
            rsc += rsum_part[w * 32 + fc];
        }
        const float inv = 1.f / (rsc + 1e-6f);
        const float S   = rsc * inv;
        const float mu  = ms * inv;
        const float sig = vs * inv - mu * mu * (2.f - S) + 1e-6f;
        float lgs = __logf(sig);
        #pragma unroll
        for (int msk = 8; msk >= 1; msk >>= 1) lgs += __shfl_xor(lgs, msk);
        const float cost = rsc * (16.f * bu[fc] + 0.5f * lgs);
        const float ao   = 1.f / (1.f + __expf(-0.001f * (ba[fc] - cost)));

        mu_tab[fc * 16 + fp]  = mu;
        i2s_tab[fc * 16 + fp] = 0.5f / sig;
        if (fp == 0) Kc_tab[fc] = 0.5f * lgs - __logf(ao);

        if (it == 2) {
            outp[(size_t)pos * 512 + tid] = mu;
            if (fp == 0) outp[147456 + (size_t)pos * 32 + fc] = ao;
        }
        __syncthreads();
    }
}

extern "C" void kernel_launch(void* const* d_in, const int* in_sizes, int n_in,
                              void* d_out, int out_size, void* d_ws, size_t ws_size,
                              hipStream_t stream) {
    (void)in_sizes; (void)n_in; (void)out_size;
    const float* x  = (const float*)d_in[0];
    const float* a  = (const float*)d_in[1];
    const float* w  = (const float*)d_in[2];
    const float* bu = (const float*)d_in[3];
    const float* ba = (const float*)d_in[4];
    float* out = (float*)d_out;

    const size_t buf_elems = (size_t)NPOS * NCH * PSTRIDE;
    const size_t need = (2 * buf_elems) * sizeof(float) + NPOS * sizeof(unsigned);
    if (ws_size < need) {
        convcaps_kernel<<<dim3(288), dim3(512), 0, stream>>>(x, a, w, bu, ba, out);
        return;
    }
    float* buf0 = (float*)d_ws;
    float* buf1 = buf0 + buf_elems;
    unsigned* cnt = (unsigned*)(buf0 + 2 * buf_elems);

    caps_acc<0><<<dim3(NPOS * NCH), dim3(256), 0, stream>>>(x, a, w, bu, ba, nullptr, buf0, out, cnt);
    caps_acc<1><<<dim3(NPOS * NCH), dim3(256), 0, stream>>>(x, a, w, bu, ba, buf0, buf1, out, cnt);
    caps_acc<2><<<dim3(NPOS * NCH), dim3(256), 0, stream>>>(x, a, w, bu, ba, buf1, buf0, out, cnt);
}

// Round 10
// 128.671 us; speedup vs baseline: 3.1039x; 3.1039x over previous
//
#include <hip/hip_runtime.h>

#define NPOS 288
#define NCH 6
#define CHUNK 48
#define CSTRIDE 36               // floats per c-row in partials (144 B, 16B-aligned)
#define PSTRIDE (32 * CSTRIDE)   // floats per (pos,chunk) record = 1152

// ---- DPP 32-lane reductions (VALU pipe; groups = lanes [0,32),[32,64)) ----
template<int CTRL>
__device__ __forceinline__ float dpp_mov(float x) {
    return __int_as_float(__builtin_amdgcn_update_dpp(
        0, __float_as_int(x), CTRL, 0xF, 0xF, true));
}
__device__ __forceinline__ float red32_max(float x) {
    x = fmaxf(x, dpp_mov<0x121>(x));
    x = fmaxf(x, dpp_mov<0x122>(x));
    x = fmaxf(x, dpp_mov<0x124>(x));
    x = fmaxf(x, dpp_mov<0x128>(x));
    return fmaxf(x, __shfl_xor(x, 16));
}
__device__ __forceinline__ float red32_sum(float x) {
    x += dpp_mov<0x121>(x);
    x += dpp_mov<0x122>(x);
    x += dpp_mov<0x124>(x);
    x += dpp_mov<0x128>(x);
    return x + __shfl_xor(x, 16);
}

#define DOT4(pa, c0, c1, c2, c3) fmaf(pa.x, c0, fmaf(pa.y, c1, fmaf(pa.z, c2, pa.w * c3)))
#define VROWS() \
    v0.x = DOT4(pa0, wa0.x, wa1.x, wa2.x, wa3.x); \
    v0.y = DOT4(pa0, wa0.y, wa1.y, wa2.y, wa3.y); \
    v0.z = DOT4(pa0, wa0.z, wa1.z, wa2.z, wa3.z); \
    v0.w = DOT4(pa0, wa0.w, wa1.w, wa2.w, wa3.w); \
    v1.x = DOT4(pa1, wa0.x, wa1.x, wa2.x, wa3.x); \
    v1.y = DOT4(pa1, wa0.y, wa1.y, wa2.y, wa3.y); \
    v1.z = DOT4(pa1, wa0.z, wa1.z, wa2.z, wa3.z); \
    v1.w = DOT4(pa1, wa0.w, wa1.w, wa2.w, wa3.w); \
    v2.x = DOT4(pa2, wa0.x, wa1.x, wa2.x, wa3.x); \
    v2.y = DOT4(pa2, wa0.y, wa1.y, wa2.y, wa3.y); \
    v2.z = DOT4(pa2, wa0.z, wa1.z, wa2.z, wa3.z); \
    v2.w = DOT4(pa2, wa0.w, wa1.w, wa2.w, wa3.w); \
    v3.x = DOT4(pa3, wa0.x, wa1.x, wa2.x, wa3.x); \
    v3.y = DOT4(pa3, wa0.y, wa1.y, wa2.y, wa3.y); \
    v3.z = DOT4(pa3, wa0.z, wa1.z, wa2.z, wa3.z); \
    v3.w = DOT4(pa3, wa0.w, wa1.w, wa2.w, wa3.w);
#define SQ4(d, v) d.x = v.x*v.x; d.y = v.y*v.y; d.z = v.z*v.z; d.w = v.w*v.w;
#define TU4(t, u, v, q, A, B) \
    t = fmaf(q.x, A.x, t); u = fmaf(v.x, B.x, u); \
    t = fmaf(q.y, A.y, t); u = fmaf(v.y, B.y, u); \
    t = fmaf(q.z, A.z, t); u = fmaf(v.z, B.z, u); \
    t = fmaf(q.w, A.w, t); u = fmaf(v.w, B.w, u);
#define RACC(mai, vai, vi, qi) \
    mai.x = fmaf(r, vi.x, mai.x); vai.x = fmaf(r, qi.x, vai.x); \
    mai.y = fmaf(r, vi.y, mai.y); vai.y = fmaf(r, qi.y, vai.y); \
    mai.z = fmaf(r, vi.z, mai.z); vai.z = fmaf(r, qi.z, vai.z); \
    mai.w = fmaf(r, vi.w, mai.w); vai.w = fmaf(r, qi.w, vai.w);
#define XRED(vi) \
    vi.x += __shfl_xor(vi.x, 32); vi.y += __shfl_xor(vi.y, 32); \
    vi.z += __shfl_xor(vi.z, 32); vi.w += __shfl_xor(vi.w, 32);

// ---------------------------------------------------------------------------
// Pipeline: 3 accumulate kernels (one per EM iteration) + separate finalize.
// Grid 1728 = 288 pos x 6 chunks of 48 n; partials in d_ws (no atomics).
// E-step expanded quadratic: lnap = 2*sum(v*B) - sum(v^2*A) - C with A=i2s,
// B=mu*i2s, C=sum(mu^2*i2s)+Kc; v^2 shared with M-step.
// PLAIN __launch_bounds__ only (R1/R4: min-waves arg => spill catastrophe).
// NO in-kernel __threadfence finalize (R8: device-scope fence on non-coherent
// per-XCD L2s = L2 writeback per block = 330us; kernel boundary is the cheap
// device-wide fence).
// R9 bench was an infra failure (container acquisition); identical resubmit.
// ---------------------------------------------------------------------------
template<int IT>
__global__ __launch_bounds__(256) void caps_acc(
    const float* __restrict__ xg,
    const float* __restrict__ ag,
    const float* __restrict__ wg,
    const float* __restrict__ bu,
    const float* __restrict__ ba,
    const float* __restrict__ pin,   // previous-iteration partials (IT>0)
    float* __restrict__ pout)        // this-iteration partials
{
    __shared__ __align__(16) float pose_s[CHUNK * 16];   // 48 n x 16 p = 3KB
    __shared__ float a_s[CHUNK];
    __shared__ __align__(16) float scratch[4 * 32 * 33]; // 4 waves x 32 c x 33
    __shared__ float rsum_part[4 * 32];
    __shared__ float i2s_tab[512];                       // A
    __shared__ float b_tab[512];                         // B = mu*i2s
    __shared__ float c_tab[32];                          // C = M2 + Kc

    const int tid = threadIdx.x;
    const int blk = blockIdx.x;
    const int pos = blk / NCH;
    const int ch  = blk - pos * NCH;
    const int bb  = pos / 36;
    const int rem = pos % 36;
    const int yy  = rem / 6;
    const int xx  = rem % 6;

    // ---- stage pose slice (48x16); 256-wide loads never cross a cell ----
    #pragma unroll
    for (int j = 0; j < 3; ++j) {
        const int e    = ch * 768 + j * 256 + tid;
        const int cell = e >> 9;
        const int off  = e & 511;
        const int kh = cell / 3, kw = cell % 3;
        pose_s[j * 256 + tid] =
            xg[(size_t)((((bb * 14) + (2 * yy + kh)) * 14 + (2 * xx + kw)) * 32) * 16 + off];
    }
    if (IT == 0) {
        if (tid < CHUNK) {
            const int e    = ch * CHUNK + tid;
            const int cell = e >> 5;
            const int bi   = e & 31;
            const int kh = cell / 3, kw = cell % 3;
            a_s[tid] = ag[(size_t)(((bb * 14) + (2 * yy + kh)) * 14 + (2 * xx + kw)) * 32 + bi];
        }
    }

    const int fc2 = tid >> 3;   // 0..31
    const int fh  = tid & 7;    // 0..7
    if (IT > 0) {
        // ---- redundant finalize of previous iteration from global partials ----
        const float* q0 = pin + (size_t)pos * (NCH * PSTRIDE) + fc2 * CSTRIDE;
        float ms0 = 0.f, ms1 = 0.f, vs0 = 0.f, vs1 = 0.f, rsc = 0.f;
        #pragma unroll
        for (int cc = 0; cc < NCH; ++cc) {
            const float* q = q0 + cc * PSTRIDE;
            const float4 m4 = *(const float4*)&q[fh * 4];
            ms0 += m4.x; ms1 += m4.y; vs0 += m4.z; vs1 += m4.w;
            rsc += q[32];
        }
        const float inv  = 1.f / (rsc + 1e-6f);
        const float S    = rsc * inv;
        const float mmu0 = ms0 * inv;
        const float mmu1 = ms1 * inv;
        const float sg0  = vs0 * inv - mmu0 * mmu0 * (2.f - S) + 1e-6f;
        const float sg1  = vs1 * inv - mmu1 * mmu1 * (2.f - S) + 1e-6f;
        const float i0   = 0.5f / sg0;
        const float i1   = 0.5f / sg1;
        float lgs = __logf(sg0) + __logf(sg1);
        float m2  = fmaf(mmu0 * mmu0, i0, mmu1 * mmu1 * i1);
        #pragma unroll
        for (int msk = 4; msk >= 1; msk >>= 1) {
            lgs += __shfl_xor(lgs, msk);
            m2  += __shfl_xor(m2, msk);
        }
        const float cost = rsc * (16.f * bu[fc2] + 0.5f * lgs);
        const float ao   = 1.f / (1.f + __expf(-0.001f * (ba[fc2] - cost)));
        i2s_tab[fc2 * 16 + fh]     = i0;
        i2s_tab[fc2 * 16 + fh + 8] = i1;
        b_tab[fc2 * 16 + fh]       = mmu0 * i0;
        b_tab[fc2 * 16 + fh + 8]   = mmu1 * i1;
        if (fh == 0) c_tab[fc2] = m2 + 0.5f * lgs - __logf(ao);
    }
    __syncthreads();

    const int c    = tid & 31;
    const int s    = tid >> 5;
    const int lane = tid & 63;
    const int wv   = tid >> 6;
    const float4* wp = (const float4*)wg;

    float4 A0, A1, A2, A3, B0, B1, B2, B3;
    float C = 0.f;
    if (IT > 0) {
        A0 = *(const float4*)&i2s_tab[c * 16 + 0];
        A1 = *(const float4*)&i2s_tab[c * 16 + 4];
        A2 = *(const float4*)&i2s_tab[c * 16 + 8];
        A3 = *(const float4*)&i2s_tab[c * 16 + 12];
        B0 = *(const float4*)&b_tab[c * 16 + 0];
        B1 = *(const float4*)&b_tab[c * 16 + 4];
        B2 = *(const float4*)&b_tab[c * 16 + 8];
        B3 = *(const float4*)&b_tab[c * 16 + 12];
        C  = c_tab[c];
    }

    float4 ma0, ma1, ma2, ma3, va0, va1, va2, va3;
    ma0 = ma1 = ma2 = ma3 = make_float4(0.f, 0.f, 0.f, 0.f);
    va0 = va1 = va2 = va3 = make_float4(0.f, 0.f, 0.f, 0.f);
    float rs = 0.f;

    const int n0 = ch * CHUNK + s * 6;
    const float4* wptr = wp + (size_t)(n0 * 32 + c) * 4;
    float4 wa0 = wptr[0], wa1 = wptr[1], wa2 = wptr[2], wa3 = wptr[3];

    #define EM_STEP_ACC(NL)                                                \
    {                                                                      \
        const float4* pp = (const float4*)&pose_s[(NL) << 4];              \
        float4 pa0 = pp[0], pa1 = pp[1], pa2 = pp[2], pa3 = pp[3];         \
        float4 v0, v1, v2, v3;                                             \
        VROWS()                                                            \
        float4 q0_, q1_, q2_, q3_;                                         \
        SQ4(q0_, v0) SQ4(q1_, v1) SQ4(q2_, v2) SQ4(q3_, v3)                \
        float r;                                                           \
        if (IT == 0) {                                                     \
            r = a_s[NL] * 0.03125f;                                        \
        } else {                                                           \
            float t01 = 0.f, u01 = 0.f, t23 = 0.f, u23 = 0.f;              \
            TU4(t01, u01, v0, q0_, A0, B0)                                 \
            TU4(t01, u01, v1, q1_, A1, B1)                                 \
            TU4(t23, u23, v2, q2_, A2, B2)                                 \
            TU4(t23, u23, v3, q3_, A3, B3)                                 \
            const float lnap = fmaf(2.f, u01 + u23, -(t01 + t23)) - C;     \
            const float m    = red32_max(lnap);                            \
            const float e    = __expf(lnap - m);                           \
            const float sum  = red32_sum(e);                               \
            r = __fdividef(e, sum);                                        \
        }                                                                  \
        rs += r;                                                           \
        RACC(ma0, va0, v0, q0_)                                            \
        RACC(ma1, va1, v1, q1_)                                            \
        RACC(ma2, va2, v2, q2_)                                            \
        RACC(ma3, va3, v3, q3_)                                            \
    }

    for (int k = 0; k < 5; ++k) {
        const float4* wnext = wptr + 128;
        float4 wn0 = wnext[0], wn1 = wnext[1], wn2 = wnext[2], wn3 = wnext[3];
        EM_STEP_ACC(s * 6 + k)
        wa0 = wn0; wa1 = wn1; wa2 = wn2; wa3 = wn3; wptr = wnext;
    }
    EM_STEP_ACC(s * 6 + 5)
    #undef EM_STEP_ACC

    // ---- reduce 8 n-slices: shfl pair, then LDS across 4 waves ----
    XRED(ma0) XRED(ma1) XRED(ma2) XRED(ma3)
    XRED(va0) XRED(va1) XRED(va2) XRED(va3)
    rs += __shfl_xor(rs, 32);
    if (lane < 32) {  // c = lane
        const int base = (wv * 32 + lane) * 33;
        scratch[base+0]=ma0.x;  scratch[base+1]=ma0.y;  scratch[base+2]=ma0.z;  scratch[base+3]=ma0.w;
        scratch[base+4]=ma1.x;  scratch[base+5]=ma1.y;  scratch[base+6]=ma1.z;  scratch[base+7]=ma1.w;
        scratch[base+8]=ma2.x;  scratch[base+9]=ma2.y;  scratch[base+10]=ma2.z; scratch[base+11]=ma2.w;
        scratch[base+12]=ma3.x; scratch[base+13]=ma3.y; scratch[base+14]=ma3.z; scratch[base+15]=ma3.w;
        scratch[base+16]=va0.x; scratch[base+17]=va0.y; scratch[base+18]=va0.z; scratch[base+19]=va0.w;
        scratch[base+20]=va1.x; scratch[base+21]=va1.y; scratch[base+22]=va1.z; scratch[base+23]=va1.w;
        scratch[base+24]=va2.x; scratch[base+25]=va2.y; scratch[base+26]=va2.z; scratch[base+27]=va2.w;
        scratch[base+28]=va3.x; scratch[base+29]=va3.y; scratch[base+30]=va3.z; scratch[base+31]=va3.w;
        rsum_part[wv * 32 + lane] = rs;
    }
    __syncthreads();

    // ---- block-level sum -> write chunk partials ([fh][ms0,ms1,vs0,vs1] rows) ----
    float ms0 = 0.f, ms1 = 0.f, vs0 = 0.f, vs1 = 0.f, rsc = 0.f;
    #pragma unroll
    for (int w = 0; w < 4; ++w) {
        const int base = (w * 32 + fc2) * 33;
        ms0 += scratch[base + fh];
        ms1 += scratch[base + fh + 8];
        vs0 += scratch[base + 16 + fh];
        vs1 += scratch[base + 16 + fh + 8];
        rsc += rsum_part[w * 32 + fc2];
    }
    float* po = pout + (size_t)(pos * NCH + ch) * PSTRIDE + fc2 * CSTRIDE;
    *(float4*)&po[fh * 4] = make_float4(ms0, ms1, vs0, vs1);
    if (fh == 0) po[32] = rsc;
}

__global__ __launch_bounds__(512) void caps_fin(
    const float* __restrict__ pin,
    const float* __restrict__ bu,
    const float* __restrict__ ba,
    float* __restrict__ outp)
{
    const int tid = threadIdx.x;
    const int pos = blockIdx.x;
    const int fc = tid >> 4, fp = tid & 15;
    const float* q0 = pin + (size_t)pos * (NCH * PSTRIDE) + fc * CSTRIDE;
    float ms = 0.f, vs = 0.f, rsc = 0.f;
    #pragma unroll
    for (int cc = 0; cc < NCH; ++cc) {
        const float* q = q0 + cc * PSTRIDE;
        ms  += q[(fp & 7) * 4 + (fp >> 3)];
        vs  += q[(fp & 7) * 4 + 2 + (fp >> 3)];
        rsc += q[32];
    }
    const float inv = 1.f / (rsc + 1e-6f);
    const float S   = rsc * inv;
    const float mu  = ms * inv;
    const float sig = vs * inv - mu * mu * (2.f - S) + 1e-6f;
    float lgs = __logf(sig);
    #pragma unroll
    for (int msk = 8; msk >= 1; msk >>= 1) lgs += __shfl_xor(lgs, msk);
    const float cost = rsc * (16.f * bu[fc] + 0.5f * lgs);
    const float ao   = 1.f / (1.f + __expf(-0.001f * (ba[fc] - cost)));
    outp[(size_t)pos * 512 + fc * 16 + fp] = mu;
    if (fp == 0) outp[147456 + (size_t)pos * 32 + fc] = ao;
}

// ---------------------------------------------------------------------------
// Fallback: single fused kernel (used only if workspace too small).
// ---------------------------------------------------------------------------
__global__ __launch_bounds__(512) void convcaps_kernel(
    const float* __restrict__ xg,
    const float* __restrict__ ag,
    const float* __restrict__ wg,
    const float* __restrict__ bu,
    const float* __restrict__ ba,
    float* __restrict__ outp)
{
    __shared__ __align__(16) float pose_s[4608];
    __shared__ float a_s[288];
    __shared__ __align__(16) float scratch[8448];
    __shared__ float rsum_part[256];
    __shared__ float mu_tab[512];
    __shared__ float i2s_tab[512];
    __shared__ float Kc_tab[32];

    const int tid = threadIdx.x;
    const int pos = blockIdx.x;
    const int bb  = pos / 36;
    const int rem = pos % 36;
    const int yy  = rem / 6;
    const int xx  = rem % 6;

    #pragma unroll
    for (int wi = 0; wi < 9; ++wi) {
        const int kh = wi / 3, kw = wi % 3;
        const float* src =
            xg + (size_t)((((bb * 14) + (2 * yy + kh)) * 14 + (2 * xx + kw)) * 32) * 16;
        pose_s[wi * 512 + tid] = src[tid];
    }
    if (tid < 288) {
        const int wi = tid >> 5, bi = tid & 31;
        const int kh = wi / 3, kw = wi % 3;
        a_s[tid] = ag[(size_t)(((bb * 14) + (2 * yy + kh)) * 14 + (2 * xx + kw)) * 32 + bi];
    }
    __syncthreads();

    const int c    = tid & 31;
    const int s    = tid >> 5;
    const int lane = tid & 63;
    const int wv   = tid >> 6;
    const float4* wp = (const float4*)wg;

    for (int it = 0; it < 3; ++it) {
        float mu_c[16], i2s_c[16], Kc = 0.f;
        if (it > 0) {
            #pragma unroll
            for (int p = 0; p < 16; ++p) {
                mu_c[p]  = mu_tab[c * 16 + p];
                i2s_c[p] = i2s_tab[c * 16 + p];
            }
            Kc = Kc_tab[c];
        }
        float macc[16], vacc[16], rs = 0.f;
        #pragma unroll
        for (int p = 0; p < 16; ++p) { macc[p] = 0.f; vacc[p] = 0.f; }

        for (int k = 0; k < 18; ++k) {
            const int n = s * 18 + k;
            const float4* pp = (const float4*)&pose_s[n << 4];
            float pf[16];
            float4 q;
            q = pp[0]; pf[0]=q.x; pf[1]=q.y; pf[2]=q.z;  pf[3]=q.w;
            q = pp[1]; pf[4]=q.x; pf[5]=q.y; pf[6]=q.z;  pf[7]=q.w;
            q = pp[2]; pf[8]=q.x; pf[9]=q.y; pf[10]=q.z; pf[11]=q.w;
            q = pp[3]; pf[12]=q.x; pf[13]=q.y; pf[14]=q.z; pf[15]=q.w;
            const int wbase = (n * 32 + c) * 4;
            float v[16];
            #pragma unroll
            for (int p = 0; p < 16; ++p) v[p] = 0.f;
            #pragma unroll
            for (int j = 0; j < 4; ++j) {
                const float4 w = wp[wbase + j];
                #pragma unroll
                for (int i = 0; i < 4; ++i) {
                    const float pj = pf[i * 4 + j];
                    v[i*4+0] = fmaf(pj, w.x, v[i*4+0]);
                    v[i*4+1] = fmaf(pj, w.y, v[i*4+1]);
                    v[i*4+2] = fmaf(pj, w.z, v[i*4+2]);
                    v[i*4+3] = fmaf(pj, w.w, v[i*4+3]);
                }
            }
            float r;
            if (it == 0) {
                r = a_s[n] * 0.03125f;
            } else {
                float t = 0.f;
                #pragma unroll
                for (int p = 0; p < 16; ++p) {
                    float d = v[p] - mu_c[p];
                    t = fmaf(d * d, i2s_c[p], t);
                }
                float lnap = -t - Kc;
                float m = lnap;
                #pragma unroll
                for (int msk = 16; msk >= 1; msk >>= 1) m = fmaxf(m, __shfl_xor(m, msk));
                float e = __expf(lnap - m);
                float sum = e;
                #pragma unroll
                for (int msk = 16; msk >= 1; msk >>= 1) sum += __shfl_xor(sum, msk);
                r = e / sum;
            }
            rs += r;
            #pragma unroll
            for (int p = 0; p < 16; ++p) {
                float rv = r * v[p];
                macc[p] += rv;
                vacc[p] = fmaf(rv, v[p], vacc[p]);
            }
        }

        #pragma unroll
        for (int p = 0; p < 16; ++p) {
            macc[p] += __shfl_xor(macc[p], 32);
            vacc[p] += __shfl_xor(vacc[p], 32);
        }
        rs += __shfl_xor(rs, 32);
        if (lane < 32) {
            const int base = (wv * 32 + lane) * 33;
            #pragma unroll
            for (int p = 0; p < 16; ++p) {
                scratch[base + p]      = macc[p];
                scratch[base + 16 + p] = vacc[p];
            }
            rsum_part[wv * 32 + lane] = rs;
        }
        __syncthreads();

        const int fc = tid >> 4, fp = tid & 15;
        float ms = 0.f, vs = 0.f, rsc = 0.f;
        #pragma unroll
        for (int w = 0; w < 8; ++w) {
            ms  += scratch[(w * 32 + fc) * 33 + fp];
            vs  += scratch[(w * 32 + fc) * 33 + 16 + fp];
            rsc += rsum_part[w * 32 + fc];
        }
        const float inv = 1.f / (rsc + 1e-6f);
        const float S   = rsc * inv;
        const float mu  = ms * inv;
        const float sig = vs * inv - mu * mu * (2.f - S) + 1e-6f;
        float lgs = __logf(sig);
        #pragma unroll
        for (int msk = 8; msk >= 1; msk >>= 1) lgs += __shfl_xor(lgs, msk);
        const float cost = rsc * (16.f * bu[fc] + 0.5f * lgs);
        const float ao   = 1.f / (1.f + __expf(-0.001f * (ba[fc] - cost)));

        mu_tab[fc * 16 + fp]  = mu;
        i2s_tab[fc * 16 + fp] = 0.5f / sig;
        if (fp == 0) Kc_tab[fc] = 0.5f * lgs - __logf(ao);

        if (it == 2) {
            outp[(size_t)pos * 512 + tid] = mu;
            if (fp == 0) outp[147456 + (size_t)pos * 32 + fc] = ao;
        }
        __syncthreads();
    }
}

extern "C" void kernel_launch(void* const* d_in, const int* in_sizes, int n_in,
                              void* d_out, int out_size, void* d_ws, size_t ws_size,
                              hipStream_t stream) {
    (void)in_sizes; (void)n_in; (void)out_size;
    const float* x  = (const float*)d_in[0];
    const float* a  = (const float*)d_in[1];
    const float* w  = (const float*)d_in[2];
    const float* bu = (const float*)d_in[3];
    const float* ba = (const float*)d_in[4];
    float* out = (float*)d_out;

    const size_t buf_elems = (size_t)NPOS * NCH * PSTRIDE;
    if (ws_size < 2 * buf_elems * sizeof(float)) {
        convcaps_kernel<<<dim3(288), dim3(512), 0, stream>>>(x, a, w, bu, ba, out);
        return;
    }
    float* buf0 = (float*)d_ws;
    float* buf1 = buf0 + buf_elems;

    caps_acc<0><<<dim3(NPOS * NCH), dim3(256), 0, stream>>>(x, a, w, bu, ba, nullptr, buf0);
    caps_acc<1><<<dim3(NPOS * NCH), dim3(256), 0, stream>>>(x, a, w, bu, ba, buf0, buf1);
    caps_acc<2><<<dim3(NPOS * NCH), dim3(256), 0, stream>>>(x, a, w, bu, ba, buf1, buf0);
    caps_fin<<<dim3(NPOS), dim3(512), 0, stream>>>(buf0, bu, ba, out);
}